// Round 6
// baseline (339.792 us; speedup 1.0000x reference)
//
#include <hip/hip_runtime.h>

typedef unsigned short ushort_t;
using bf16x8 = __attribute__((ext_vector_type(8))) short;
using f32x4  = __attribute__((ext_vector_type(4))) float;

#define DEV static __device__ __forceinline__

DEV unsigned short f2bf(float f) {
  union { float f; unsigned u; } a; a.f = f;
  unsigned r = a.u + 0x7fffu + ((a.u >> 16) & 1u);
  return (unsigned short)(r >> 16);
}
DEV float bf2f(unsigned short u) {
  union { unsigned u; float f; } a; a.u = ((unsigned)u) << 16;
  return a.f;
}
DEV void load_lds16(const void* g, void* l) {
  __builtin_amdgcn_global_load_lds(
      (const __attribute__((address_space(1))) void*)g,
      (__attribute__((address_space(3))) void*)l, 16, 0, 0);
}

// ---------------------------------------------------------------- casts
__global__ __launch_bounds__(256) void cast_kernel(
    const float* __restrict__ src, ushort_t* __restrict__ dst, int n4) {
  int i = blockIdx.x * 256 + threadIdx.x;
  if (i >= n4) return;
  float4 f = ((const float4*)src)[i];
  ushort4 o;
  o.x = f2bf(f.x); o.y = f2bf(f.y); o.z = f2bf(f.z); o.w = f2bf(f.w);
  ((ushort4*)dst)[i] = o;
}

// ---------------------------------------------------------------- rope tables
__global__ __launch_bounds__(256) void rope_tables_kernel(float* __restrict__ tab) {
  int idx = blockIdx.x * 256 + threadIdx.x;   // < 2048*64
  int s = idx >> 6, i = idx & 63;
  float rate = exp2f(-13.287712379549449f * ((float)(2 * i) * (1.0f / 128.0f)));
  float ang = (float)s * rate;
  tab[idx * 2]     = cosf(ang);
  tab[idx * 2 + 1] = sinf(ang);
}

// ---------------------------------------------------------------- balanced GEMM
// C = A * B^T. A[M][K], B[N][K] bf16 row-major. Tile BM x BN, BK=32, 256 threads
// (4 waves, 2m x 2n; wave tile BM/2 x BN/2). Double-buffered LDS; one barrier per
// K-tile: stage(t+1) issued at top, __syncthreads (drains vmcnt) at bottom ->
// issue-to-wait = one full K-tile. Swizzle: 16B-slot ^= (row>>1)&3 on source+read.
template<int BM, int BN, int OUTF32>
__global__ __launch_bounds__(256, 2) void gemm_bal(
    const ushort_t* __restrict__ A, const ushort_t* __restrict__ Bm,
    void* __restrict__ C, int M, int N, int K) {
  constexpr int MF   = BM / 32;          // m-frags per wave
  constexpr int NF   = BN / 32;          // n-frags per wave
  constexpr int NCA  = BM / 64;          // A stage chunks (64 rows each)
  constexpr int NCB  = BN / 64;
  constexpr int NC   = NCA + NCB;
  constexpr int ABY  = BM * 64;          // A region bytes
  constexpr int BUFB = (BM + BN) * 64;
  __shared__ __align__(16) char lds[2 * BUFB];

  // bijective chunked XCD swizzle (grid % 8 == 0 by construction)
  const int nby = M / BM;
  const int nwg = nby * (N / BN);
  const int orig = blockIdx.x;
  const int wgid = (orig & 7) * (nwg >> 3) + (orig >> 3);
  const int bm = (wgid % nby) * BM;
  const int bn = (wgid / nby) * BN;

  const int tid = threadIdx.x;
  const int lane = tid & 63;
  const int wave = tid >> 6;
  const int ql = lane & 15, lk = lane >> 4;
  const int wm = wave >> 1, wn = wave & 1;

  f32x4 acc[MF][NF];
#pragma unroll
  for (int m = 0; m < MF; ++m)
#pragma unroll
    for (int n = 0; n < NF; ++n) acc[m][n] = (f32x4){0.f, 0.f, 0.f, 0.f};

  // staging: chunk = 64 rows x 32 k (4 KB); thread: row rin = tid>>2, slot tid&3
  const int rin  = tid >> 2;
  const int sswz = ((tid & 3) ^ ((rin >> 1) & 3)) * 16;
  const size_t rb = (size_t)K * 2;
  const char* src[NC];
#pragma unroll
  for (int c = 0; c < NCA; ++c)
    src[c] = (const char*)A + (size_t)(bm + c * 64 + rin) * rb + sswz;
#pragma unroll
  for (int c = 0; c < NCB; ++c)
    src[NCA + c] = (const char*)Bm + (size_t)(bn + c * 64 + rin) * rb + sswz;
  char* const ldsc = (char*)lds;
  const int dT = tid * 16;

  // fragment read offsets (row*64 + (lk ^ ((row>>1)&3))*16)
  int aOff[MF], bOff[NF];
#pragma unroll
  for (int m = 0; m < MF; ++m) {
    const int r = wm * (BM / 2) + m * 16 + ql;
    aOff[m] = r * 64 + ((lk ^ ((r >> 1) & 3)) * 16);
  }
#pragma unroll
  for (int n = 0; n < NF; ++n) {
    const int r = wn * (BN / 2) + n * 16 + ql;
    bOff[n] = ABY + r * 64 + ((lk ^ ((r >> 1) & 3)) * 16);
  }

#define STAGE(BB, KT) do {                                   \
    char* d_ = ldsc + (BB) * BUFB + dT;                      \
    const size_t ko_ = (size_t)(KT) * 64;                    \
    _Pragma("unroll")                                        \
    for (int c = 0; c < NC; ++c)                             \
      load_lds16(src[c] + ko_, d_ + c * 4096);               \
  } while (0)
#define MFMA(a, b, c) __builtin_amdgcn_mfma_f32_16x16x32_bf16(a, b, c, 0, 0, 0)

  const int ns = K >> 5;
  STAGE(0, 0);
  __syncthreads();

  for (int t = 0; t < ns; ++t) {
    const int nk = (t + 1 < ns) ? t + 1 : t;   // clamped dummy keeps counts uniform
    STAGE((t + 1) & 1, nk);
    const char* sb = ldsc + (t & 1) * BUFB;
    bf16x8 bF[NF], aF[MF];
#pragma unroll
    for (int n = 0; n < NF; ++n) bF[n] = *(const bf16x8*)(sb + bOff[n]);
#pragma unroll
    for (int m = 0; m < MF; ++m) aF[m] = *(const bf16x8*)(sb + aOff[m]);
    __builtin_amdgcn_s_setprio(1);
#pragma unroll
    for (int m = 0; m < MF; ++m)
#pragma unroll
      for (int n = 0; n < NF; ++n)
        acc[m][n] = MFMA(aF[m], bF[n], acc[m][n]);
    __builtin_amdgcn_s_setprio(0);
    __syncthreads();   // drains vmcnt(0): next tile staged & visible
  }
#undef STAGE
#undef MFMA

#pragma unroll
  for (int m = 0; m < MF; ++m)
#pragma unroll
    for (int i = 0; i < 4; ++i) {
      const size_t row = (size_t)(bm + wm * (BM / 2) + m * 16 + lk * 4 + i);
#pragma unroll
      for (int n = 0; n < NF; ++n) {
        const size_t col = (size_t)(bn + wn * (BN / 2) + n * 16 + ql);
        float v = acc[m][n][i];
        if (OUTF32) ((float*)C)[row * (size_t)N + col] = v;
        else        ((ushort_t*)C)[row * (size_t)N + col] = f2bf(v);
      }
    }
}

// ---------------------------------------------------------------- RoPE + RMS + relayout
__global__ __launch_bounds__(256) void rope_rms_kernel(
    const ushort_t* __restrict__ qkv, ushort_t* __restrict__ q,
    ushort_t* __restrict__ k, ushort_t* __restrict__ vt,
    const float* __restrict__ tab) {
  const int lane = threadIdx.x & 63;
  const int row  = blockIdx.x * 4 + (threadIdx.x >> 6);  // (((b*S+s)*3)+which)*16+h
  const int h = row & 15;
  int t = row >> 4;
  const int which = t % 3; t /= 3;
  const int s = t & 2047;
  const int b = t >> 11;
  const size_t src = ((size_t)(b * 2048 + s)) * 6144 + which * 2048 + h * 128 + lane * 2;
  ushort2 xv = *(const ushort2*)&qkv[src];
  if (which == 2) {
    size_t vbase = ((size_t)((b * 16 + h) * 128 + lane * 2)) * 2048 + s;
    vt[vbase]        = xv.x;
    vt[vbase + 2048] = xv.y;
    return;
  }
  float lo = bf2f(xv.x), ro = bf2f(xv.y);
  const float2 cs = *(const float2*)&tab[(s * 64 + lane) * 2];
  float l2 = lo * cs.x - ro * cs.y;
  float r2 = lo * cs.y + ro * cs.x;
  float ss = l2 * l2 + r2 * r2;
#pragma unroll
  for (int off = 1; off < 64; off <<= 1) ss += __shfl_xor(ss, off);
  float inv = rsqrtf(ss * (1.0f / 128.0f) + 1.1920928955078125e-07f);
  if (which == 0) inv *= 0.1275174398f;  // (1/sqrt(128)) * log2(e)
  lo = l2 * inv; ro = r2 * inv;
  ushort_t* dst = (which == 0) ? q : k;
  ushort2 o; o.x = f2bf(lo); o.y = f2bf(ro);
  *(ushort2*)&dst[(((size_t)(b * 16 + h)) * 2048 + s) * 128 + lane * 2] = o;
}

// ---------------------------------------------------------------- flash attention (causal)
// grid (bh=32, yp=8). 4 waves x 32 q-rows (2 fragment groups share every K/V LDS
// read -> reads/MFMA = 0.5). QBLK=128, KBLK=64. Pass pairing (qt, 15-qt) -> 36
// K-tiles/block uniform. K/V double-buffered, stage(kt+1) overlaps compute(kt).
__global__ __launch_bounds__(256, 1) void attn_kernel(
    const ushort_t* __restrict__ Q, const ushort_t* __restrict__ K,
    const ushort_t* __restrict__ VT, ushort_t* __restrict__ Y) {
  __shared__ __align__(16) ushort_t sK[2][64 * 128];
  __shared__ __align__(16) ushort_t sV[2][128 * 64];
  const int bh = blockIdx.x;
  const int yp = blockIdx.y;
  const int wave = threadIdx.x >> 6, lane = threadIdx.x & 63;
  const int ql = lane & 15, lk = lane >> 4;
  const size_t hq = (size_t)bh * 2048 * 128;
  const int b = bh >> 4, h = bh & 15;

  const char* kB = (const char*)(K + hq);
  const char* vB = (const char*)(VT + hq);
  const char* kSrc[4]; char* kDst[4];
  const char* vSrc[4]; char* vDst[4];
#pragma unroll
  for (int t = 0; t < 4; ++t) {
    int r = wave * 16 + t * 4 + (lane >> 4);
    int kgr = r >> 4, lkr = (r >> 2) & 3, ir = r & 3;
    int rho = (kgr >> 1) * 32 + lkr * 8 + (kgr & 1) * 4 + ir;   // key-permutation
    kSrc[t] = kB + rho * 256 + (((lane & 15) * 16) ^ ((r & 7) << 4));
    kDst[t] = (char*)sK + (wave * 256 + t * 64 + lane) * 16;
    int d = wave * 32 + t * 8 + (lane >> 3);
    vSrc[t] = vB + (size_t)d * 4096 + (((lane & 7) * 16) ^ ((d & 7) << 4));
    vDst[t] = (char*)sV + (wave * 256 + t * 64 + lane) * 16;
  }

#define STAGEKV(KT, BB) do {                                         \
    _Pragma("unroll")                                                \
    for (int t_ = 0; t_ < 4; ++t_) {                                 \
      load_lds16(kSrc[t_] + (size_t)(KT) * 16384, kDst[t_] + (BB) * 16384); \
      load_lds16(vSrc[t_] + (KT) * 128, vDst[t_] + (BB) * 16384);    \
    }                                                                \
  } while (0)

  int buf = 0;
  STAGEKV(0, 0);
  __syncthreads();

  for (int pass = 0; pass < 2; ++pass) {
    const int qt = pass ? (15 - yp) : yp;
    const int ktmax = 2 * qt + 1;
    const int q0 = qt * 128 + wave * 32 + ql;   // group g row = q0 + g*16

    bf16x8 qf[2][4];
#pragma unroll
    for (int g = 0; g < 2; ++g)
#pragma unroll
      for (int ks = 0; ks < 4; ++ks)
        qf[g][ks] = *(const bf16x8*)&Q[hq + (size_t)(q0 + g * 16) * 128 + ks * 32 + lk * 8];

    f32x4 acc[2][8];
#pragma unroll
    for (int g = 0; g < 2; ++g)
#pragma unroll
      for (int dg = 0; dg < 8; ++dg) acc[g][dg] = (f32x4){0.f, 0.f, 0.f, 0.f};
    float mrow[2] = {-3.0e38f, -3.0e38f}, lsum[2] = {0.f, 0.f};

    for (int kt = 0; kt <= ktmax; ++kt) {
      // prefetch next K-tile (cross-pass: pass0's last prefetches pass1's kt=0)
      const int nk = (kt < ktmax) ? kt + 1 : (pass == 0 ? 0 : ktmax);
      STAGEKV(nk, buf ^ 1);
      const char* sKb = (const char*)sK + buf * 16384;
      const char* sVb = (const char*)sV + buf * 16384;

      // S^T = K . Q^T for both groups (kf read once, used twice)
      f32x4 st[2][4];
#pragma unroll
      for (int g = 0; g < 2; ++g)
#pragma unroll
        for (int kg = 0; kg < 4; ++kg) st[g][kg] = (f32x4){0.f, 0.f, 0.f, 0.f};
#pragma unroll
      for (int kg = 0; kg < 4; ++kg) {
        const int row = kg * 16 + ql;
        const int rswz = (row & 7) << 4;
#pragma unroll
        for (int ks = 0; ks < 4; ++ks) {
          bf16x8 kf = *(const bf16x8*)(sKb + row * 256 + ((ks * 64 + lk * 16) ^ rswz));
          st[0][kg] = __builtin_amdgcn_mfma_f32_16x16x32_bf16(kf, qf[0][ks], st[0][kg], 0, 0, 0);
          st[1][kg] = __builtin_amdgcn_mfma_f32_16x16x32_bf16(kf, qf[1][ks], st[1][kg], 0, 0, 0);
        }
      }
      // per-group softmax + pack
      bf16x8 pb[2][2];
#pragma unroll
      for (int g = 0; g < 2; ++g) {
        const int q = q0 + g * 16;
        float sv[4][4]; float mp = -3.0e38f;
#pragma unroll
        for (int kg = 0; kg < 4; ++kg) {
          const int kl = ((kg >> 1) << 5) + lk * 8 + ((kg & 1) << 2);
#pragma unroll
          for (int i = 0; i < 4; ++i) {
            const int key = kt * 64 + kl + i;
            float v = (key <= q) ? st[g][kg][i] : -3.0e38f;
            sv[kg][i] = v;
            mp = fmaxf(mp, v);
          }
        }
        mp = fmaxf(mp, __shfl_xor(mp, 16));
        mp = fmaxf(mp, __shfl_xor(mp, 32));
        const float mn = fmaxf(mrow[g], mp);
        const float corr = exp2f(mrow[g] - mn);
        mrow[g] = mn;
        float p[4][4]; float rs = 0.f;
#pragma unroll
        for (int kg = 0; kg < 4; ++kg)
#pragma unroll
          for (int i = 0; i < 4; ++i) {
            float e = exp2f(sv[kg][i] - mn);
            p[kg][i] = e; rs += e;
          }
        rs += __shfl_xor(rs, 16);
        rs += __shfl_xor(rs, 32);
        lsum[g] = lsum[g] * corr + rs;
#pragma unroll
        for (int dg = 0; dg < 8; ++dg)
#pragma unroll
          for (int i = 0; i < 4; ++i) acc[g][dg][i] *= corr;
#pragma unroll
        for (int c = 0; c < 2; ++c) {
          union { bf16x8 v; ushort_t u[8]; } pk;
#pragma unroll
          for (int j = 0; j < 8; ++j) pk.u[j] = f2bf(p[2 * c + (j >> 2)][j & 3]);
          pb[g][c] = pk.v;
        }
      }
      // O^T += V^T . P^T (vf read once, used twice)
#pragma unroll
      for (int dg = 0; dg < 8; ++dg) {
        const int d = dg * 16 + ql;
        const int dswz = (d & 7) << 4;
#pragma unroll
        for (int c = 0; c < 2; ++c) {
          bf16x8 vf = *(const bf16x8*)(sVb + d * 128 + ((c * 64 + lk * 16) ^ dswz));
          acc[0][dg] = __builtin_amdgcn_mfma_f32_16x16x32_bf16(vf, pb[0][c], acc[0][dg], 0, 0, 0);
          acc[1][dg] = __builtin_amdgcn_mfma_f32_16x16x32_bf16(vf, pb[1][c], acc[1][dg], 0, 0, 0);
        }
      }
      __syncthreads();   // drains vmcnt: next tile staged; also fences LDS reuse
      buf ^= 1;
    }

    // epilogue: Y (B,S,E) bf16, both groups
#pragma unroll
    for (int g = 0; g < 2; ++g) {
      const float inv = 1.0f / lsum[g];
      const size_t orow = ((size_t)(b * 2048 + q0 + g * 16)) * 2048 + h * 128;
#pragma unroll
      for (int dg = 0; dg < 8; ++dg) {
        ushort4 o;
        o.x = f2bf(acc[g][dg][0] * inv);
        o.y = f2bf(acc[g][dg][1] * inv);
        o.z = f2bf(acc[g][dg][2] * inv);
        o.w = f2bf(acc[g][dg][3] * inv);
        *(ushort4*)&Y[orow + dg * 16 + lk * 4] = o;
      }
    }
  }
#undef STAGEKV
}

// ---------------------------------------------------------------- launch
extern "C" void kernel_launch(void* const* d_in, const int* in_sizes, int n_in,
                              void* d_out, int out_size, void* d_ws, size_t ws_size,
                              hipStream_t stream) {
  const float* x     = (const float*)d_in[0];
  const float* wqkv  = (const float*)d_in[1];
  const float* wproj = (const float*)d_in[2];
  float* out = (float*)d_out;
  char* ws = (char*)d_ws;

  ushort_t* x_bf     = (ushort_t*)(ws);                // 16,777,216
  ushort_t* wqkv_bf  = (ushort_t*)(ws + 16777216);     // 25,165,824
  ushort_t* wproj_bf = (ushort_t*)(ws + 41943040);     //  8,388,608
  ushort_t* qkv_bf   = (ushort_t*)(ws + 50331648);     // 50,331,648 (reused as y)
  ushort_t* q_bf     = (ushort_t*)(ws + 100663296);    // 16,777,216
  ushort_t* k_bf     = (ushort_t*)(ws + 117440512);    // 16,777,216
  ushort_t* vt_bf    = (ushort_t*)(ws + 134217728);    // 16,777,216 (B,H,D,S)
  float*    tab      = (float*)(ws + 150994944);       //  1,048,576
  if (ws_size < 152043520u) return;

  cast_kernel<<<8192, 256, 0, stream>>>(x, x_bf, 2097152);
  cast_kernel<<<12288, 256, 0, stream>>>(wqkv, wqkv_bf, 3145728);
  cast_kernel<<<4096, 256, 0, stream>>>(wproj, wproj_bf, 1048576);
  rope_tables_kernel<<<512, 256, 0, stream>>>(tab);

  // qkv = x @ w_qkv^T  (4096 x 6144 x 2048): tile 256x128, grid 768 = 3/CU, 2-resident
  gemm_bal<256, 128, 0><<<768, 256, 0, stream>>>(x_bf, wqkv_bf, qkv_bf, 4096, 6144, 2048);

  rope_rms_kernel<<<49152, 256, 0, stream>>>(qkv_bf, q_bf, k_bf, vt_bf, tab);

  attn_kernel<<<dim3(32, 8), 256, 0, stream>>>(q_bf, k_bf, vt_bf, qkv_bf /* y */);

  // out = y @ w_proj^T  (4096 x 2048 x 2048): tile 128x128, grid 512 = 2/CU resident
  gemm_bal<128, 128, 1><<<512, 256, 0, stream>>>(qkv_bf, wproj_bf, out, 4096, 2048, 2048);
}

// Round 7
// 313.111 us; speedup vs baseline: 1.0852x; 1.0852x over previous
//
#include <hip/hip_runtime.h>

typedef unsigned short ushort_t;
using bf16x8 = __attribute__((ext_vector_type(8))) short;
using f32x4  = __attribute__((ext_vector_type(4))) float;

#define DEV static __device__ __forceinline__

DEV unsigned short f2bf(float f) {
  union { float f; unsigned u; } a; a.f = f;
  unsigned r = a.u + 0x7fffu + ((a.u >> 16) & 1u);
  return (unsigned short)(r >> 16);
}
DEV float bf2f(unsigned short u) {
  union { unsigned u; float f; } a; a.u = ((unsigned)u) << 16;
  return a.f;
}
DEV void load_lds16(const void* g, void* l) {
  __builtin_amdgcn_global_load_lds(
      (const __attribute__((address_space(1))) void*)g,
      (__attribute__((address_space(3))) void*)l, 16, 0, 0);
}

// ---------------------------------------------------------------- casts
__global__ __launch_bounds__(256) void cast_kernel(
    const float* __restrict__ src, ushort_t* __restrict__ dst, int n4) {
  int i = blockIdx.x * 256 + threadIdx.x;
  if (i >= n4) return;
  float4 f = ((const float4*)src)[i];
  ushort4 o;
  o.x = f2bf(f.x); o.y = f2bf(f.y); o.z = f2bf(f.z); o.w = f2bf(f.w);
  ((ushort4*)dst)[i] = o;
}

// ---------------------------------------------------------------- rope tables
__global__ __launch_bounds__(256) void rope_tables_kernel(float* __restrict__ tab) {
  int idx = blockIdx.x * 256 + threadIdx.x;   // < 2048*64
  int s = idx >> 6, i = idx & 63;
  float rate = exp2f(-13.287712379549449f * ((float)(2 * i) * (1.0f / 128.0f)));
  float ang = (float)s * rate;
  tab[idx * 2]     = cosf(ang);
  tab[idx * 2 + 1] = sinf(ang);
}

// ---------------------------------------------------------------- 3-buffer pipelined GEMM
// C = A * B^T. A[M][K], B[N][K] bf16 row-major. Tile BM x BN, BK=32, 512 threads,
// 8 waves (WM x WN). 3 LDS buffers: compute t, t+1 landed, t+2 in flight.
// Per tile: 2 phases {ds_read frags; stage; barrier; setprio; MFMA half; setprio;
// barrier}, one counted vmcnt(L) per tile (drains exactly tile t+1's loads).
// Swizzle: 16B-slot ^= (row>>1)&3 on pre-swizzled source + reads (structural-min banks).
template<int BM, int BN, int WM, int WN, int OUTF32>
__global__ __launch_bounds__(512, 1) void gemm3b(
    const ushort_t* __restrict__ A, const ushort_t* __restrict__ Bm,
    void* __restrict__ C, int M, int N, int K) {
  constexpr int MF   = BM / WM / 16;
  constexpr int NF   = BN / WN / 16;
  constexpr int ABY  = BM * 64;            // A region bytes per buffer (BK=32)
  constexpr int BBY  = BN * 64;
  constexpr int BUFB = ABY + BBY;
  constexpr int LA   = ABY / 8192;         // A loads/thread (512 thr x 16 B)
  constexpr int LB   = BBY / 8192;
  constexpr int L    = LA + LB;
  __shared__ __align__(16) char lds[3 * BUFB];

  // bijective chunked XCD swizzle (grid % 8 == 0 by construction)
  const int nby = M / BM;
  const int nwg = nby * (N / BN);
  const int orig = blockIdx.x;
  const int wgid = (orig & 7) * (nwg >> 3) + (orig >> 3);
  const int bm = (wgid % nby) * BM;
  const int bn = (wgid / nby) * BN;

  const int tid  = threadIdx.x;
  const int lane = tid & 63;
  const int wave = tid >> 6;
  const int ql = lane & 15, lk = lane >> 4;
  const int wm = wave / WN, wn = wave % WN;

  f32x4 acc[MF][NF];
#pragma unroll
  for (int m = 0; m < MF; ++m)
#pragma unroll
    for (int n = 0; n < NF; ++n) acc[m][n] = (f32x4){0.f, 0.f, 0.f, 0.f};

  // ---- staging geometry: load l covers LDS bytes [l*8192 + tid*16); row = off/64
  const size_t rb = (size_t)K * 2;
  const char* srcA[LA]; const char* srcB[LB];
#pragma unroll
  for (int l = 0; l < LA; ++l) {
    const int r = l * 128 + (tid >> 2);
    const int slot = (tid & 3) ^ ((r >> 1) & 3);
    srcA[l] = (const char*)A + (size_t)(bm + r) * rb + slot * 16;
  }
#pragma unroll
  for (int l = 0; l < LB; ++l) {
    const int r = l * 128 + (tid >> 2);
    const int slot = (tid & 3) ^ ((r >> 1) & 3);
    srcB[l] = (const char*)Bm + (size_t)(bn + r) * rb + slot * 16;
  }
  char* const ldsc = (char*)lds;
  const int dT = tid * 16;

  // ---- fragment read offsets
  int aOff[MF], bOff[NF];
#pragma unroll
  for (int m = 0; m < MF; ++m) {
    const int r = wm * (BM / WM) + m * 16 + ql;
    aOff[m] = r * 64 + ((lk ^ ((r >> 1) & 3)) * 16);
  }
#pragma unroll
  for (int n = 0; n < NF; ++n) {
    const int r = wn * (BN / WN) + n * 16 + ql;
    bOff[n] = ABY + r * 64 + ((lk ^ ((r >> 1) & 3)) * 16);
  }

#define STAGE_A(SB, KT) do {                                        \
    _Pragma("unroll")                                               \
    for (int l = 0; l < LA; ++l)                                    \
      load_lds16(srcA[l] + (size_t)(KT) * 64, (SB) + l * 8192 + dT);\
  } while (0)
#define STAGE_B(SB, KT) do {                                        \
    _Pragma("unroll")                                               \
    for (int l = 0; l < LB; ++l)                                    \
      load_lds16(srcB[l] + (size_t)(KT) * 64, (SB) + ABY + l * 8192 + dT); \
  } while (0)
#define MFMA(a, b, c) __builtin_amdgcn_mfma_f32_16x16x32_bf16(a, b, c, 0, 0, 0)

  const int ns = K >> 5;

  // prologue: stage tiles 0 and 1; drain tile 0 (leave tile 1 in flight)
  STAGE_A(ldsc, 0); STAGE_B(ldsc, 0);
  STAGE_A(ldsc + BUFB, 1); STAGE_B(ldsc + BUFB, 1);
  asm volatile("s_waitcnt vmcnt(%0)" :: "n"(L) : "memory");
  __builtin_amdgcn_s_barrier();

  int cbi = 0;
  for (int t = 0; t < ns; ++t) {
    const char* cb = ldsc + cbi * BUFB;
    const int sbi = (cbi + 2 >= 3) ? cbi - 1 : cbi + 2;
    char* sb = ldsc + sbi * BUFB;
    const int kt2 = (t + 2 < ns) ? t + 2 : ns - 1;   // clamped dummy keeps counts uniform

    // ---- phase 0: read all A frags + first half B; stage A of t+2
    bf16x8 aF[MF], bF[NF];
#pragma unroll
    for (int m = 0; m < MF; ++m) aF[m] = *(const bf16x8*)(cb + aOff[m]);
#pragma unroll
    for (int n = 0; n < NF / 2; ++n) bF[n] = *(const bf16x8*)(cb + bOff[n]);
    asm volatile("" ::: "memory");   // pin reads before staging/barrier
    STAGE_A(sb, kt2);
    __builtin_amdgcn_s_barrier();
    __builtin_amdgcn_s_setprio(1);
#pragma unroll
    for (int n = 0; n < NF / 2; ++n)
#pragma unroll
      for (int m = 0; m < MF; ++m)
        acc[m][n] = MFMA(aF[m], bF[n], acc[m][n]);
    __builtin_amdgcn_s_setprio(0);
    __builtin_amdgcn_s_barrier();

    // ---- phase 1: read second half B; stage B of t+2; drain tile t+1
#pragma unroll
    for (int n = NF / 2; n < NF; ++n) bF[n] = *(const bf16x8*)(cb + bOff[n]);
    asm volatile("" ::: "memory");
    STAGE_B(sb, kt2);
    asm volatile("s_waitcnt vmcnt(%0)" :: "n"(L) : "memory");
    __builtin_amdgcn_s_barrier();
    __builtin_amdgcn_s_setprio(1);
#pragma unroll
    for (int n = NF / 2; n < NF; ++n)
#pragma unroll
      for (int m = 0; m < MF; ++m)
        acc[m][n] = MFMA(aF[m], bF[n], acc[m][n]);
    __builtin_amdgcn_s_setprio(0);
    __builtin_amdgcn_s_barrier();

    cbi = (cbi + 1 >= 3) ? 0 : cbi + 1;
  }
  asm volatile("s_waitcnt vmcnt(0)" ::: "memory");
#undef STAGE_A
#undef STAGE_B
#undef MFMA

#pragma unroll
  for (int m = 0; m < MF; ++m)
#pragma unroll
    for (int i = 0; i < 4; ++i) {
      const size_t row = (size_t)(bm + wm * (BM / WM) + m * 16 + lk * 4 + i);
#pragma unroll
      for (int n = 0; n < NF; ++n) {
        const size_t col = (size_t)(bn + wn * (BN / WN) + n * 16 + ql);
        float v = acc[m][n][i];
        if (OUTF32) ((float*)C)[row * (size_t)N + col] = v;
        else        ((ushort_t*)C)[row * (size_t)N + col] = f2bf(v);
      }
    }
}

// ---------------------------------------------------------------- RoPE + RMS + relayout
__global__ __launch_bounds__(256) void rope_rms_kernel(
    const ushort_t* __restrict__ qkv, ushort_t* __restrict__ q,
    ushort_t* __restrict__ k, ushort_t* __restrict__ vt,
    const float* __restrict__ tab) {
  const int lane = threadIdx.x & 63;
  const int row  = blockIdx.x * 4 + (threadIdx.x >> 6);  // (((b*S+s)*3)+which)*16+h
  const int h = row & 15;
  int t = row >> 4;
  const int which = t % 3; t /= 3;
  const int s = t & 2047;
  const int b = t >> 11;
  const size_t src = ((size_t)(b * 2048 + s)) * 6144 + which * 2048 + h * 128 + lane * 2;
  ushort2 xv = *(const ushort2*)&qkv[src];
  if (which == 2) {
    size_t vbase = ((size_t)((b * 16 + h) * 128 + lane * 2)) * 2048 + s;
    vt[vbase]        = xv.x;
    vt[vbase + 2048] = xv.y;
    return;
  }
  float lo = bf2f(xv.x), ro = bf2f(xv.y);
  const float2 cs = *(const float2*)&tab[(s * 64 + lane) * 2];
  float l2 = lo * cs.x - ro * cs.y;
  float r2 = lo * cs.y + ro * cs.x;
  float ss = l2 * l2 + r2 * r2;
#pragma unroll
  for (int off = 1; off < 64; off <<= 1) ss += __shfl_xor(ss, off);
  float inv = rsqrtf(ss * (1.0f / 128.0f) + 1.1920928955078125e-07f);
  if (which == 0) inv *= 0.1275174398f;  // (1/sqrt(128)) * log2(e)
  lo = l2 * inv; ro = r2 * inv;
  ushort_t* dst = (which == 0) ? q : k;
  ushort2 o; o.x = f2bf(lo); o.y = f2bf(ro);
  *(ushort2*)&dst[(((size_t)(b * 16 + h)) * 2048 + s) * 128 + lane * 2] = o;
}

// ---------------------------------------------------------------- flash attention (causal)
// (round-5 version, verbatim: grid (32,16), 4 waves x 16 q-rows, 2-per-CU residency)
__global__ __launch_bounds__(256) void attn_kernel(
    const ushort_t* __restrict__ Q, const ushort_t* __restrict__ K,
    const ushort_t* __restrict__ VT, ushort_t* __restrict__ Y) {
  __shared__ __align__(16) ushort_t sK[64 * 128];
  __shared__ __align__(16) ushort_t sV[128 * 64];
  const int bh = blockIdx.x;
  const int yp = blockIdx.y;
  const int wave = threadIdx.x >> 6, lane = threadIdx.x & 63;
  const int ql = lane & 15, lk = lane >> 4;
  const size_t hq = (size_t)bh * 2048 * 128;
  const int b = bh >> 4, h = bh & 15;

  const char* kB = (const char*)(K + hq);
  const char* vB = (const char*)(VT + hq);
  const char* kSrc[4]; char* kDst[4];
  const char* vSrc[4]; char* vDst[4];
#pragma unroll
  for (int t = 0; t < 4; ++t) {
    int r = wave * 16 + t * 4 + (lane >> 4);
    int kgr = r >> 4, lkr = (r >> 2) & 3, ir = r & 3;
    int rho = (kgr >> 1) * 32 + lkr * 8 + (kgr & 1) * 4 + ir;   // key-permutation
    kSrc[t] = kB + rho * 256 + (((lane & 15) * 16) ^ ((r & 7) << 4));
    kDst[t] = (char*)sK + (wave * 256 + t * 64 + lane) * 16;
    int d = wave * 32 + t * 8 + (lane >> 3);
    vSrc[t] = vB + (size_t)d * 4096 + (((lane & 7) * 16) ^ ((d & 7) << 4));
    vDst[t] = (char*)sV + (wave * 256 + t * 64 + lane) * 16;
  }

  for (int pass = 0; pass < 2; ++pass) {
    const int qt = pass ? (31 - yp) : yp;
    const int q = qt * 64 + wave * 16 + ql;

    bf16x8 qf[4];
#pragma unroll
    for (int ks = 0; ks < 4; ++ks)
      qf[ks] = *(const bf16x8*)&Q[hq + (size_t)q * 128 + ks * 32 + lk * 8];

    f32x4 acc[8];
#pragma unroll
    for (int g = 0; g < 8; ++g) acc[g] = (f32x4){0.f, 0.f, 0.f, 0.f};
    float mrow = -3.0e38f, lsum = 0.f;

    for (int kt = 0; kt <= qt; ++kt) {
#pragma unroll
      for (int t = 0; t < 4; ++t) {
        load_lds16(kSrc[t] + (size_t)kt * 16384, kDst[t]);
        load_lds16(vSrc[t] + kt * 128, vDst[t]);
      }
      __syncthreads();

      // S^T = K . Q^T   (lane&15 = q-row; keys permuted by rho)
      f32x4 st[4];
#pragma unroll
      for (int kg = 0; kg < 4; ++kg) st[kg] = (f32x4){0.f, 0.f, 0.f, 0.f};
#pragma unroll
      for (int kg = 0; kg < 4; ++kg) {
        const int row = kg * 16 + ql;
        const int rswz = (row & 7) << 4;
#pragma unroll
        for (int ks = 0; ks < 4; ++ks) {
          bf16x8 kf = *(const bf16x8*)((const char*)sK + row * 256 + ((ks * 64 + lk * 16) ^ rswz));
          st[kg] = __builtin_amdgcn_mfma_f32_16x16x32_bf16(kf, qf[ks], st[kg], 0, 0, 0);
        }
      }
      float sv[4][4]; float mp = -3.0e38f;
#pragma unroll
      for (int kg = 0; kg < 4; ++kg) {
        const int kl = ((kg >> 1) << 5) + lk * 8 + ((kg & 1) << 2);
#pragma unroll
        for (int i = 0; i < 4; ++i) {
          const int key = kt * 64 + kl + i;
          float v = (key <= q) ? st[kg][i] : -3.0e38f;
          sv[kg][i] = v;
          mp = fmaxf(mp, v);
        }
      }
      mp = fmaxf(mp, __shfl_xor(mp, 16));
      mp = fmaxf(mp, __shfl_xor(mp, 32));
      const float mn = fmaxf(mrow, mp);
      const float corr = exp2f(mrow - mn);
      mrow = mn;
      float p[4][4]; float rs = 0.f;
#pragma unroll
      for (int kg = 0; kg < 4; ++kg)
#pragma unroll
        for (int i = 0; i < 4; ++i) {
          float e = exp2f(sv[kg][i] - mn);
          p[kg][i] = e; rs += e;
        }
      rs += __shfl_xor(rs, 16);
      rs += __shfl_xor(rs, 32);
      lsum = lsum * corr + rs;
#pragma unroll
      for (int g = 0; g < 8; ++g)
#pragma unroll
        for (int i = 0; i < 4; ++i) acc[g][i] *= corr;
      bf16x8 pb[2];
#pragma unroll
      for (int c = 0; c < 2; ++c) {
        union { bf16x8 v; ushort_t u[8]; } pk;
#pragma unroll
        for (int j = 0; j < 8; ++j) pk.u[j] = f2bf(p[2 * c + (j >> 2)][j & 3]);
        pb[c] = pk.v;
      }
#pragma unroll
      for (int dg = 0; dg < 8; ++dg) {
        const int d = dg * 16 + ql;
        const int dswz = (d & 7) << 4;
#pragma unroll
        for (int c = 0; c < 2; ++c) {
          bf16x8 vf = *(const bf16x8*)((const char*)sV + d * 128 + ((c * 64 + lk * 16) ^ dswz));
          acc[dg] = __builtin_amdgcn_mfma_f32_16x16x32_bf16(vf, pb[c], acc[dg], 0, 0, 0);
        }
      }
      __syncthreads();
    }

    const float inv = 1.0f / lsum;
    const size_t orow = ((size_t)(b * 2048 + q)) * 2048 + h * 128;
#pragma unroll
    for (int dg = 0; dg < 8; ++dg) {
      ushort4 o;
      o.x = f2bf(acc[dg][0] * inv);
      o.y = f2bf(acc[dg][1] * inv);
      o.z = f2bf(acc[dg][2] * inv);
      o.w = f2bf(acc[dg][3] * inv);
      *(ushort4*)&Y[orow + dg * 16 + lk * 4] = o;
    }
  }
}

// ---------------------------------------------------------------- launch
extern "C" void kernel_launch(void* const* d_in, const int* in_sizes, int n_in,
                              void* d_out, int out_size, void* d_ws, size_t ws_size,
                              hipStream_t stream) {
  const float* x     = (const float*)d_in[0];
  const float* wqkv  = (const float*)d_in[1];
  const float* wproj = (const float*)d_in[2];
  float* out = (float*)d_out;
  char* ws = (char*)d_ws;

  ushort_t* x_bf     = (ushort_t*)(ws);                // 16,777,216
  ushort_t* wqkv_bf  = (ushort_t*)(ws + 16777216);     // 25,165,824
  ushort_t* wproj_bf = (ushort_t*)(ws + 41943040);     //  8,388,608
  ushort_t* qkv_bf   = (ushort_t*)(ws + 50331648);     // 50,331,648 (reused as y)
  ushort_t* q_bf     = (ushort_t*)(ws + 100663296);    // 16,777,216
  ushort_t* k_bf     = (ushort_t*)(ws + 117440512);    // 16,777,216
  ushort_t* vt_bf    = (ushort_t*)(ws + 134217728);    // 16,777,216 (B,H,D,S)
  float*    tab      = (float*)(ws + 150994944);       //  1,048,576
  if (ws_size < 152043520u) return;

  cast_kernel<<<8192, 256, 0, stream>>>(x, x_bf, 2097152);
  cast_kernel<<<12288, 256, 0, stream>>>(wqkv, wqkv_bf, 3145728);
  cast_kernel<<<4096, 256, 0, stream>>>(wproj, wproj_bf, 1048576);
  rope_tables_kernel<<<512, 256, 0, stream>>>(tab);

  // qkv = x @ w_qkv^T  (4096 x 6144 x 2048): tile 256x256, 8 waves (2x4), grid 384
  gemm3b<256, 256, 2, 4, 0><<<384, 512, 0, stream>>>(x_bf, wqkv_bf, qkv_bf, 4096, 6144, 2048);

  rope_rms_kernel<<<49152, 256, 0, stream>>>(qkv_bf, q_bf, k_bf, vt_bf, tab);

  attn_kernel<<<dim3(32, 16), 256, 0, stream>>>(q_bf, k_bf, vt_bf, qkv_bf /* y */);

  // out = y @ w_proj^T  (4096 x 2048 x 2048): tile 256x128, 8 waves (4x2), grid 256 = 1/CU
  gemm3b<256, 128, 4, 2, 1><<<256, 512, 0, stream>>>(qkv_bf, wproj_bf, out, 4096, 2048, 2048);
}